// Round 1
// baseline (349.981 us; speedup 1.0000x reference)
//
#include <hip/hip_runtime.h>

// Problem constants (fixed by setup_inputs): B=1, C=32, H=96, W=192, max_disp=192
constexpr int C  = 32;
constexpr int D  = 64;    // max_disp / 3
constexpr int H  = 96;
constexpr int W  = 192;
constexpr int W4 = W / 4; // 48

// Output: (1, 2C, D, H, W) fp32.
//   ch <  C : out = x[ch][h][w]      * (w >= d)
//   ch >= C : out = y[ch-C][h][w-d]  * (w >= d)
// One thread per float4 of output; tid == output float4 index (coalesced stores).
__global__ __launch_bounds__(256) void fusion_kernel(const float* __restrict__ x,
                                                     const float* __restrict__ y,
                                                     float4* __restrict__ out) {
    const int tid = blockIdx.x * blockDim.x + threadIdx.x;
    const int w4   = tid % W4;
    int rest       = tid / W4;
    const int h    = rest % H;
    rest          /= H;
    const int d    = rest % D;
    const int ch   = rest / D;      // [0, 2C) — wave-uniform (stride 294912)
    const int w    = w4 * 4;

    float4 v;
    if (ch < C) {
        v = *(const float4*)(&x[(ch * H + h) * W + w]);
    } else {
        const float* yr = &y[((ch - C) * H + h) * W];
        // masked lanes (w+i < d) get overwritten with 0 below; clamp index to stay in-bounds
        v.x = yr[max(w + 0 - d, 0)];
        v.y = yr[max(w + 1 - d, 0)];
        v.z = yr[max(w + 2 - d, 0)];
        v.w = yr[max(w + 3 - d, 0)];
    }
    if (w < d) {               // only boundary/masked float4s pay the per-lane test
        if (w + 0 < d) v.x = 0.f;
        if (w + 1 < d) v.y = 0.f;
        if (w + 2 < d) v.z = 0.f;
        if (w + 3 < d) v.w = 0.f;
    }
    out[tid] = v;
}

extern "C" void kernel_launch(void* const* d_in, const int* in_sizes, int n_in,
                              void* d_out, int out_size, void* d_ws, size_t ws_size,
                              hipStream_t stream) {
    const float* x = (const float*)d_in[0];
    const float* y = (const float*)d_in[1];
    float4* out    = (float4*)d_out;

    constexpr int total4 = 2 * C * D * H * W4;        // 18,874,368 float4 stores
    constexpr int block  = 256;
    constexpr int grid   = total4 / block;            // 73,728 (divides exactly)
    fusion_kernel<<<grid, block, 0, stream>>>(x, y, out);
}

// Round 3
// 305.115 us; speedup vs baseline: 1.1470x; 1.1470x over previous
//
#include <hip/hip_runtime.h>

// Problem constants (fixed by setup_inputs): B=1, C=32, H=96, W=192, max_disp=192
constexpr int C      = 32;
constexpr int D      = 64;    // max_disp / 3
constexpr int H      = 96;
constexpr int W      = 192;
constexpr int W4     = W / 4;      // 48
constexpr int DCHUNK = 16;         // d-values per thread
constexpr int NCHUNK = D / DCHUNK; // 4

// native vector type — __builtin_nontemporal_store requires ext_vector_type,
// not HIP's float4 class
typedef float f4 __attribute__((ext_vector_type(4)));

// Output: (1, 2C, D, H, W) fp32.
//   ch <  C : out = x[ch][h][w]      * (w >= d)
//   ch >= C : out = y[ch-C][h][w-d]  * (w >= d)
// Each thread owns one (chunk, ch, h, w4) and writes DCHUNK float4s (one per d).
// Stores are contiguous 1 KB per wave per iteration (lanes span w4,h).
__global__ __launch_bounds__(256) void fusion_kernel(const float* __restrict__ x,
                                                     const float* __restrict__ y,
                                                     float* __restrict__ out) {
    const int tid  = blockIdx.x * blockDim.x + threadIdx.x;
    const int w4   = tid % W4;
    int rest       = tid / W4;
    const int h    = rest % H;
    rest          /= H;
    const int ch   = rest % (2 * C);
    const int d0   = (rest / (2 * C)) * DCHUNK;   // chunk base
    const int w    = w4 * 4;

    // output element offset of (ch, d0, h, w); fits in int (75.5M total)
    int outoff = (ch * D + d0) * (H * W) + h * W + w;

    if (ch < C) {
        const f4 xv = *(const f4*)(&x[(ch * H + h) * W + w]);
        #pragma unroll
        for (int i = 0; i < DCHUNK; ++i) {
            const int d = d0 + i;
            f4 v = xv;
            if (w < d) {
                if (w + 0 < d) v.x = 0.f;
                if (w + 1 < d) v.y = 0.f;
                if (w + 2 < d) v.z = 0.f;
                if (w + 3 < d) v.w = 0.f;
            }
            __builtin_nontemporal_store(v, (f4*)(&out[outoff + i * (H * W)]));
        }
    } else {
        const float* yr = &y[((ch - C) * H + h) * W];
        // sliding register window: v = y[w-d .. w+3-d] (clamped; clamped comps are masked)
        f4 v;
        v.x = yr[max(w + 0 - d0, 0)];
        v.y = yr[max(w + 1 - d0, 0)];
        v.z = yr[max(w + 2 - d0, 0)];
        v.w = yr[max(w + 3 - d0, 0)];
        #pragma unroll
        for (int i = 0; i < DCHUNK; ++i) {
            const int d = d0 + i;
            f4 s = v;
            if (w < d) {
                if (w + 0 < d) s.x = 0.f;
                if (w + 1 < d) s.y = 0.f;
                if (w + 2 < d) s.z = 0.f;
                if (w + 3 < d) s.w = 0.f;
            }
            __builtin_nontemporal_store(s, (f4*)(&out[outoff + i * (H * W)]));
            // slide window to d+1: shift right, bring in y[w-(d+1)]
            v.w = v.z; v.z = v.y; v.y = v.x;
            v.x = yr[max(w - d - 1, 0)];
        }
    }
}

extern "C" void kernel_launch(void* const* d_in, const int* in_sizes, int n_in,
                              void* d_out, int out_size, void* d_ws, size_t ws_size,
                              hipStream_t stream) {
    const float* x = (const float*)d_in[0];
    const float* y = (const float*)d_in[1];
    float* out     = (float*)d_out;

    constexpr int total  = 2 * C * H * W4 * NCHUNK;   // 1,179,648 threads
    constexpr int block  = 256;
    constexpr int grid   = total / block;             // 4608 blocks = 18/CU exactly
    fusion_kernel<<<grid, block, 0, stream>>>(x, y, out);
}